// Round 1
// baseline (880.873 us; speedup 1.0000x reference)
//
#include <hip/hip_runtime.h>
#include <math.h>

#define NEG_K 32
#define TEMP 0.07f

// One block per loss row l (loss_size = 512 blocks, 256 threads = 4 waves).
// Stage anchor in LDS; each wave computes a strided subset of the 33 dot
// products (j=0 positive, j=1..32 negatives); thread 0 does logsumexp and
// atomically accumulates the per-row loss into d_out.
__global__ __launch_bounds__(256) void infonce_kernel(
    const float* __restrict__ hs,
    const int*   __restrict__ selection,
    const int*   __restrict__ mask,
    const float* __restrict__ neg_noise,
    float*       __restrict__ out,
    int B, int S, int H, int valid_size, int loss_size)
{
    const int l    = blockIdx.x;
    const int tid  = threadIdx.x;
    const int lane = tid & 63;
    const int wave = tid >> 6;

    __shared__ float s_anchor[768];           // H = 768 for this problem
    __shared__ float s_logits[NEG_K + 1];
    __shared__ int   s_red[4];

    // ---- length[l] = sum(mask[l, :]) ----
    int msum = 0;
    for (int s = tid; s < S; s += blockDim.x)
        msum += mask[(size_t)l * S + s];
    #pragma unroll
    for (int off = 32; off > 0; off >>= 1)
        msum += __shfl_xor(msum, off, 64);
    if (lane == 0) s_red[wave] = msum;

    // ---- stage anchor row into LDS (float4, coalesced) ----
    const int sel = selection[l];
    const float4* a4  = (const float4*)(hs + ((size_t)l * S + sel) * (size_t)H);
    float4*       sa4 = (float4*)s_anchor;
    const int nvec = H >> 2;                  // 192
    for (int i = tid; i < nvec; i += blockDim.x)
        sa4[i] = a4[i];

    __syncthreads();

    const int  len = s_red[0] + s_red[1] + s_red[2] + s_red[3];
    const bool sir = (sel >= 1) && (sel <= len - 1);
    const int  n_valid = sir ? (len - 2) : (len - 1);
    const float nvf = (float)n_valid;

    // ---- 33 dot products, wave-strided ----
    for (int j = wave; j < NEG_K + 1; j += 4) {
        const float* v;
        if (j == 0) {
            v = hs + ((size_t)(valid_size + l) * S + sel) * (size_t)H;
        } else {
            // Exact float32 replication of the JAX index math:
            // u = floor(noise * n_valid); cand = u+1; bump if >= sel.
            float noise = neg_noise[(size_t)l * NEG_K + (j - 1)];
            int u = (int)floorf(noise * nvf);
            int cand = u + 1;
            if (sir && cand >= sel) cand++;
            v = hs + ((size_t)l * S + cand) * (size_t)H;
        }
        const float4* v4 = (const float4*)v;
        float p = 0.f;
        for (int i = lane; i < nvec; i += 64) {   // 3 iterations at H=768
            float4 a = sa4[i];
            float4 b = v4[i];
            p += a.x * b.x + a.y * b.y + a.z * b.z + a.w * b.w;
        }
        #pragma unroll
        for (int off = 32; off > 0; off >>= 1)
            p += __shfl_xor(p, off, 64);
        if (lane == 0) s_logits[j] = p;
    }
    __syncthreads();

    // ---- logsumexp over 33 logits, accumulate loss ----
    if (tid == 0) {
        float lg[NEG_K + 1];
        float mx = -INFINITY;
        #pragma unroll
        for (int j = 0; j < NEG_K + 1; ++j) {
            lg[j] = s_logits[j] / TEMP;
            mx = fmaxf(mx, lg[j]);
        }
        float se = 0.f;
        #pragma unroll
        for (int j = 0; j < NEG_K + 1; ++j)
            se += expf(lg[j] - mx);
        float lse = mx + logf(se);
        float loss_l = lse - lg[0];
        atomicAdd(out, loss_l / (float)B);
        if (l == 0) {
            // rows [loss_size, B): all-zero logits -> -log_softmax[0] = log(33)
            atomicAdd(out, (float)(B - loss_size) * logf((float)(NEG_K + 1)) / (float)B);
        }
    }
}

extern "C" void kernel_launch(void* const* d_in, const int* in_sizes, int n_in,
                              void* d_out, int out_size, void* d_ws, size_t ws_size,
                              hipStream_t stream) {
    const float* hs        = (const float*)d_in[0];
    const int*   selection = (const int*)  d_in[1];
    const int*   mask      = (const int*)  d_in[2];
    const float* neg_noise = (const float*)d_in[3];
    // d_in[4] holds valid_size on device; derive everything host-side from sizes.
    const int B         = in_sizes[1];               // selection: (B,)
    const int S         = in_sizes[2] / B;           // mask: (B, S)
    const int H         = in_sizes[0] / (B * S);     // hidden_states: (B, S, H)
    const int loss_size = in_sizes[3] / NEG_K;       // neg_noise: (loss_size, NEG_K)
    const int valid_size = B - loss_size;

    hipMemsetAsync(d_out, 0, sizeof(float), stream);
    infonce_kernel<<<dim3(loss_size), dim3(256), 0, stream>>>(
        hs, selection, mask, neg_noise, (float*)d_out,
        B, S, H, valid_size, loss_size);
}